// Round 5
// baseline (1971.809 us; speedup 1.0000x reference)
//
#include <hip/hip_runtime.h>
#include <hip/hip_bf16.h>

// Match numpy: no FMA contraction anywhere that feeds the Jacobi argmax.
#pragma clang fp contract(off)

#define N 4096
#define CIN 64
#define COUT 64
#define ITERS 10

typedef unsigned long long u64;

// pack (value, col j) -> u64 key: max == (greater value) or (equal value, smaller j)
__device__ __forceinline__ u64 packkey(float v, unsigned j) {
    return ((u64)__float_as_uint(v) << 32) | (u64)(unsigned)(~j);
}

// Fused: deg[r] += 1, A[r,c] += 1 (exact small ints in f32)
__global__ void edges_k(const int* __restrict__ ei, float* __restrict__ deg,
                        float* __restrict__ a, int E) {
    int e = blockIdx.x * 256 + threadIdx.x;
    if (e < E) {
        int r = ei[e];
        int c = ei[E + e];
        atomicAdd(&deg[r], 1.0f);
        atomicAdd(&a[(size_t)r * N + c], 1.0f);
    }
}

__global__ void dinv_k(const float* __restrict__ deg, float* __restrict__ dinv) {
    int i = blockIdx.x * 256 + threadIdx.x;
    if (i < N) {
        float d = deg[i];
        dinv[i] = (d > 0.0f) ? (1.0f / sqrtf(d)) : 0.0f;  // correctly-rounded = numpy
    }
}

__global__ void init_y_k(const float* __restrict__ x, float* __restrict__ y) {
    int idx = blockIdx.x * 256 + threadIdx.x;
    if (idx < N * CIN) y[idx] = x[idx];
}

// Transpose weights to [i][o] layout for coalesced lane-o access in spectral_k.
__global__ void prepw_k(const float* __restrict__ hh, const float* __restrict__ cw,
                        const float* __restrict__ rw, const float* __restrict__ iw,
                        float2* __restrict__ hcT, float4* __restrict__ rwT,
                        float4* __restrict__ iwT) {
    int idx = blockIdx.x * 256 + threadIdx.x;   // 4096 = i*64+o
    int i = idx >> 6, o = idx & 63;
    int src = o * 64 + i;
    hcT[idx] = make_float2(hh[src], cw[src]);
    rwT[idx] = make_float4(rw[src * 4 + 0], rw[src * 4 + 1], rw[src * 4 + 2], rw[src * 4 + 3]);
    iwT[idx] = make_float4(iw[src * 4 + 0], iw[src * 4 + 1], iw[src * 4 + 2], iw[src * 4 + 3]);
}

// Finisher: all blocks fence+count; last block reduces rowmax[] -> pivot (k,l),
// computes rotation params (exact reference op order), applies y-rot, resets counter.
template<int BS>
__device__ __forceinline__ void pivot_finish(
        float* a, float* __restrict__ y, u64* __restrict__ rowmax,
        unsigned* counter, unsigned nblocks,
        int* rotk, int* rotl, float* rotc, float* rotsv,
        int write_it, int apply_y) {
    int t = threadIdx.x;
    __threadfence();          // every thread: make its global writes device-visible
    __syncthreads();
    __shared__ unsigned slast;
    if (t == 0) slast = (atomicAdd(counter, 1u) == nblocks - 1u) ? 1u : 0u;
    __syncthreads();
    if (!slast) return;
    // Global pivot reduce over rowmax (atomic reads: cross-XCD same-kernel writes)
    u64 bkey = 0ull;
    for (int r = t; r < N; r += BS) {
        u64 p = atomicMax(&rowmax[r], 0ull);
        unsigned vb = (unsigned)(p >> 32);
        unsigned j = (~(unsigned)p) & 4095u;
        unsigned flat = (unsigned)r * (unsigned)N + j;
        u64 key = ((u64)vb << 32) | (u64)(unsigned)(~flat);
        if (key > bkey) bkey = key;
    }
    __shared__ u64 sp[BS];
    sp[t] = bkey;
    __syncthreads();
    for (int off = BS / 2; off > 0; off >>= 1) {
        if (t < off) { if (sp[t + off] > sp[t]) sp[t] = sp[t + off]; }
        __syncthreads();
    }
    __shared__ int skk, sll;
    __shared__ float scc, sss;
    if (t == 0) {
        unsigned flat = ~(unsigned)sp[0];
        int k = (int)((flat >> 12) & 4095u);
        int l = (int)(flat & 4095u);
        float akl = atomicAdd(&a[(size_t)k * N + l], 0.0f);
        float akk = atomicAdd(&a[(size_t)k * N + k], 0.0f);
        float all = atomicAdd(&a[(size_t)l * N + l], 0.0f);
        float aDiff = all - akk;
        float akl_safe = (akl == 0.0f) ? 1.0f : akl;
        float aDiff_safe = (aDiff == 0.0f) ? 1.0f : aDiff;
        float phi = aDiff / (2.0f * akl_safe);
        float t2 = 1.0f / (fabsf(phi) + sqrtf(phi * phi + 1.0f));
        t2 = (phi < 0.0f) ? -t2 : t2;
        float t1 = akl / aDiff_safe;
        float tt = (fabsf(akl) < fabsf(aDiff) * 1e-36f) ? t1 : t2;
        float cv = 1.0f / sqrtf(tt * tt + 1.0f);
        float sval = tt * cv;
        rotk[write_it] = k; rotl[write_it] = l;
        rotc[write_it] = cv; rotsv[write_it] = sval;
        skk = k; sll = l; scc = cv; sss = sval;
        atomicExch(counter, 0u);     // reset for next kernel
    }
    __syncthreads();
    if (apply_y && t < CIN) {        // incremental U^T x (G^T on rows k,l)
        int k = skk, l = sll;
        float c = scc, s = sss;
        float yk = y[k * CIN + t], yl = y[l * CIN + t];
        y[k * CIN + t] = c * yk - s * yl;
        y[l * CIN + t] = s * yk + c * yl;
    }
}

// a[i,j] = (i==j?1:0) - (dinv[i]*A_ij)*dinv[j]; per-row max (val, first-j) -> rowmax[i];
// finisher computes pivot 0 and applies y-rot 0.
__global__ void __launch_bounds__(256) formL_rowmax_k(
        float* __restrict__ a, const float* __restrict__ dinv,
        float* __restrict__ y, u64* __restrict__ rowmax, unsigned* counter,
        int* rotk, int* rotl, float* rotc, float* rotsv) {
    const int i = blockIdx.x;            // one row per block
    const int t = threadIdx.x;
    const float di = dinv[i];
    const size_t rowoff = (size_t)i * N;
    u64 bkey = packkey(0.0f, 0u);        // ref: masked zeros -> first zero at j=0
#pragma unroll
    for (int sIt = 0; sIt < 4; ++sIt) {
        int j0 = 4 * t + 1024 * sIt;
        float4 v4 = *reinterpret_cast<const float4*>(a + rowoff + j0);
        float4 dj = *reinterpret_cast<const float4*>(dinv + j0);
        float4 r;
        r.x = ((j0 + 0 == i) ? 1.0f : 0.0f) - ((di * v4.x) * dj.x);
        r.y = ((j0 + 1 == i) ? 1.0f : 0.0f) - ((di * v4.y) * dj.y);
        r.z = ((j0 + 2 == i) ? 1.0f : 0.0f) - ((di * v4.z) * dj.z);
        r.w = ((j0 + 3 == i) ? 1.0f : 0.0f) - ((di * v4.w) * dj.w);
        *reinterpret_cast<float4*>(a + rowoff + j0) = r;
        if (j0 + 0 > i) { u64 kk = packkey(fabsf(r.x), j0 + 0); if (kk > bkey) bkey = kk; }
        if (j0 + 1 > i) { u64 kk = packkey(fabsf(r.y), j0 + 1); if (kk > bkey) bkey = kk; }
        if (j0 + 2 > i) { u64 kk = packkey(fabsf(r.z), j0 + 2); if (kk > bkey) bkey = kk; }
        if (j0 + 3 > i) { u64 kk = packkey(fabsf(r.w), j0 + 3); if (kk > bkey) bkey = kk; }
    }
    __shared__ u64 red[256];
    red[t] = bkey;
    __syncthreads();
    for (int off = 128; off > 0; off >>= 1) {
        if (t < off) { if (red[t + off] > red[t]) red[t] = red[t + off]; }
        __syncthreads();
    }
    if (t == 0) rowmax[i] = red[0];
    pivot_finish<256>(a, y, rowmax, counter, gridDim.x,
                      rotk, rotl, rotc, rotsv, 0, 1);
}

// One block per row. Applies rotation `it` (disjoint writes), maintains rowmax,
// finisher selects pivot it+1 and applies y-rot it+1 (if any).
__global__ void __launch_bounds__(128) step_k(
        float* __restrict__ a, float* __restrict__ y, u64* __restrict__ rowmax,
        unsigned* counter,
        int* rotk, int* rotl, float* rotc, float* rotsv, int it) {
    const int i = blockIdx.x;
    const int t = threadIdx.x;
    const int k = rotk[it], l = rotl[it];
    const float c = rotc[it], s = rotsv[it];
    __shared__ float sh_a2kk, sh_a2ll, sh_nik, sh_nil;
    __shared__ int sh_mode;
    __shared__ u64 red[128];
    __shared__ u64 red2[128];

    if (i == k) {
        // Row-pair rescan (rows k and l). 2x2 block replayed in exact ref order.
        if (t == 0) {
            float akk = a[(size_t)k * N + k], akl = a[(size_t)k * N + l];
            float alk = a[(size_t)l * N + k], all = a[(size_t)l * N + l];
            float a1kk = c * akk - s * akl;   // col update i=k
            float a1kl = s * akk + c * akl;
            float a1lk = c * alk - s * all;   // col update i=l
            float a1ll = s * alk + c * all;
            sh_a2kk = c * a1kk - s * a1lk;    // row update diag
            sh_a2ll = s * a1kl + c * a1ll;
        }
        __syncthreads();
        float a2kk = sh_a2kk, a2ll = sh_a2ll;
        u64 bk = packkey(0.0f, 0u), bl = packkey(0.0f, 0u);
        for (int sIt = 0; sIt < 8; ++sIt) {
            int j0 = 4 * t + 512 * sIt;
            float4 rk4 = *reinterpret_cast<const float4*>(a + (size_t)k * N + j0);
            float4 rl4 = *reinterpret_cast<const float4*>(a + (size_t)l * N + j0);
            float4 nk4, nl4;
#pragma unroll
            for (int m = 0; m < 4; ++m) {
                int j = j0 + m;
                float rk = (&rk4.x)[m], rl = (&rl4.x)[m];
                float nk, nl;
                if (j == k)      { nk = a2kk; nl = 0.0f; }
                else if (j == l) { nk = 0.0f; nl = a2ll; }
                else             { nk = c * rk - s * rl; nl = s * rk + c * rl; }
                (&nk4.x)[m] = nk; (&nl4.x)[m] = nl;
                if (j > k) { u64 kk = packkey(fabsf(nk), j); if (kk > bk) bk = kk; }
                if (j > l) { u64 kk = packkey(fabsf(nl), j); if (kk > bl) bl = kk; }
            }
            *reinterpret_cast<float4*>(a + (size_t)k * N + j0) = nk4;
            *reinterpret_cast<float4*>(a + (size_t)l * N + j0) = nl4;
        }
        red[t] = bk; red2[t] = bl;
        __syncthreads();
        for (int off = 64; off > 0; off >>= 1) {
            if (t < off) {
                if (red[t + off] > red[t]) red[t] = red[t + off];
                if (red2[t + off] > red2[t]) red2[t] = red2[t + off];
            }
            __syncthreads();
        }
        if (t == 0) { rowmax[k] = red[0]; rowmax[l] = red2[0]; }
    } else if (i != l) {
        // Column update on (i,k),(i,l) + rowmax merge / dirty rescan.
        if (t == 0) {
            float aik = a[(size_t)i * N + k], ail = a[(size_t)i * N + l];
            float nik = c * aik - s * ail, nil = s * aik + c * ail;
            a[(size_t)i * N + k] = nik;
            a[(size_t)i * N + l] = nil;
            u64 rm = rowmax[i];
            unsigned j = (~(unsigned)rm) & 4095u;
            int dirty = ((k > i && j == (unsigned)k) || (l > i && j == (unsigned)l));
            if (!dirty) {
                u64 key = rm;
                if (k > i) { u64 kk = packkey(fabsf(nik), k); if (kk > key) key = kk; }
                if (l > i) { u64 kk = packkey(fabsf(nil), l); if (kk > key) key = kk; }
                if (key != rm) rowmax[i] = key;
                sh_mode = 0;
            } else {
                sh_mode = 1; sh_nik = nik; sh_nil = nil;
            }
        }
        __syncthreads();
        if (sh_mode) {
            float nik = sh_nik, nil = sh_nil;
            u64 bkey = packkey(0.0f, 0u);
            for (int sIt = 0; sIt < 8; ++sIt) {
                int j0 = 4 * t + 512 * sIt;
                float4 v4 = *reinterpret_cast<const float4*>(a + (size_t)i * N + j0);
#pragma unroll
                for (int m = 0; m < 4; ++m) {
                    int j = j0 + m;
                    float v = (j == k) ? nik : (j == l) ? nil : (&v4.x)[m];
                    if (j > i) { u64 kk = packkey(fabsf(v), j); if (kk > bkey) bkey = kk; }
                }
            }
            red[t] = bkey;
            __syncthreads();
            for (int off = 64; off > 0; off >>= 1) {
                if (t < off) { if (red[t + off] > red[t]) red[t] = red[t + off]; }
                __syncthreads();
            }
            if (t == 0) rowmax[i] = red[0];
        }
    }
    pivot_finish<128>(a, y, rowmax, counter, gridDim.x,
                      rotk, rotl, rotc, rotsv, it + 1, (it + 1) < ITERS);
}

// z[n,o] = sum_i g(o,i,n) * y[n,i]; transcendental-free:
// cos(2*atan(1/hw)) = (hw^2-1)/(hw^2+1), sin = 2hw/(hw^2+1); Chebyshev for j=2..4.
__global__ void __launch_bounds__(1024) spectral_k(
        const float* __restrict__ a, const float* __restrict__ y,
        const float2* __restrict__ hcT, const float4* __restrict__ rwT,
        const float4* __restrict__ iwT, float* __restrict__ z) {
    int o = threadIdx.x & 63;
    int nl = threadIdx.x >> 6;          // 0..15
    int n = blockIdx.x * 16 + nl;
    __shared__ float saux[16][CIN];
    saux[nl][o] = y[n * CIN + o];
    __syncthreads();
    float wn = a[(size_t)n * 4097u];    // diagonal
    const float C2 = -0.41614683654714241f;   // cos(2.0)
    const float S2 = 0.90929742682568170f;    // sin(2.0)
    float acc = 0.0f;
    for (int i = 0; i < CIN; ++i) {
        float2 hc = hcT[i * 64 + o];
        float hw = hc.x * wn;
        float t2v = hw * hw;
        float inv = 1.0f / (t2v + 1.0f);
        float c1 = (t2v - 1.0f) * inv;
        float s1 = (2.0f * hw) * inv;
        if (!(hw > 1e-5f)) { c1 = C2; s1 = S2; }
        float4 rwv = rwT[i * 64 + o];
        float4 iwv = iwT[i * 64 + o];
        float g = hc.y;
        float cj = c1, sj = s1;
        g += rwv.x * cj - iwv.x * sj;
        float cn = cj * c1 - sj * s1; float sn = sj * c1 + cj * s1; cj = cn; sj = sn;
        g += rwv.y * cj - iwv.y * sj;
        cn = cj * c1 - sj * s1; sn = sj * c1 + cj * s1; cj = cn; sj = sn;
        g += rwv.z * cj - iwv.z * sj;
        cn = cj * c1 - sj * s1; sn = sj * c1 + cj * s1; cj = cn; sj = sn;
        g += rwv.w * cj - iwv.w * sj;
        acc += g * saux[nl][i];
    }
    z[(size_t)n * COUT + o] = acc;
}

// output = U @ out.T : apply G_10 ... G_1 to z rows (each thread owns one column).
__global__ void finalrot_k(float* __restrict__ z,
                           const int* __restrict__ rotk, const int* __restrict__ rotl,
                           const float* __restrict__ rotc, const float* __restrict__ rotsv) {
    int col = threadIdx.x;  // 0..63
    for (int i = ITERS - 1; i >= 0; --i) {
        int k = rotk[i], l = rotl[i];
        float c = rotc[i], s = rotsv[i];
        float zk = z[k * COUT + col];
        float zl = z[l * COUT + col];
        z[k * COUT + col] = c * zk + s * zl;   // (G z)[k]
        z[l * COUT + col] = -s * zk + c * zl;  // (G z)[l]
    }
}

__global__ void store_k(const float* __restrict__ z, const float* __restrict__ bias,
                        float* __restrict__ out) {
    int idx = blockIdx.x * 256 + threadIdx.x;
    if (idx < N * COUT) {
        int o = idx & 63;
        out[idx] = z[idx] + bias[o];
    }
}

extern "C" void kernel_launch(void* const* d_in, const int* in_sizes, int n_in,
                              void* d_out, int out_size, void* d_ws, size_t ws_size,
                              hipStream_t stream) {
    const float* x   = (const float*)d_in[0];
    const int*   ei  = (const int*)d_in[1];
    const float* rw  = (const float*)d_in[2];
    const float* iw  = (const float*)d_in[3];
    const float* hh  = (const float*)d_in[4];
    const float* cw  = (const float*)d_in[5];
    const float* bias= (const float*)d_in[6];
    float* out = (float*)d_out;

    // Workspace carve. [a | deg | counter+pad | dinv | rowmax | y | z | wT | rot]
    float* a    = (float*)d_ws;                   // 16777216 f32 (64 MB)
    float* deg  = a + (size_t)N * N;              // 4096
    unsigned* counter = (unsigned*)(deg + N);     // 1 (+3 pad, keeps 16B alignment)
    float* dinv = (float*)(counter + 4);          // 4096 (16B aligned)
    u64* rowmax = (u64*)(dinv + N);               // 4096 u64 (32 KB)
    float* y    = (float*)(rowmax + N);           // 262144 : U^T x
    float* z    = y + N * CIN;                    // 262144 : out.T then U*out.T
    float2* hcT = (float2*)(z + N * COUT);        // 4096 float2
    float4* rwT = (float4*)(hcT + 4096);          // 4096 float4
    float4* iwT = rwT + 4096;                     // 4096 float4
    int*   rotk = (int*)(iwT + 4096);             // 16
    int*   rotl = rotk + 16;                      // 16
    float* rotc = (float*)(rotl + 16);            // 16
    float* rotsv= rotc + 16;                      // 16

    int E = in_sizes[1] / 2;                      // 200000 (row half of edge_index)

    // zero a + deg + counter in one memset (contiguous)
    hipMemsetAsync(a, 0, (size_t)N * N * 4 + N * 4 + 16, stream);

    int eb = (E + 255) / 256;
    edges_k<<<eb, 256, 0, stream>>>(ei, deg, a, E);
    dinv_k<<<16, 256, 0, stream>>>(deg, dinv);
    prepw_k<<<16, 256, 0, stream>>>(hh, cw, rw, iw, hcT, rwT, iwT);
    init_y_k<<<1024, 256, 0, stream>>>(x, y);

    formL_rowmax_k<<<N, 256, 0, stream>>>(a, dinv, y, rowmax, counter,
                                          rotk, rotl, rotc, rotsv);
    for (int it = 0; it < ITERS; ++it) {
        step_k<<<N, 128, 0, stream>>>(a, y, rowmax, counter,
                                      rotk, rotl, rotc, rotsv, it);
    }

    spectral_k<<<N / 16, 1024, 0, stream>>>(a, y, hcT, rwT, iwT, z);
    finalrot_k<<<1, 64, 0, stream>>>(z, rotk, rotl, rotc, rotsv);
    store_k<<<1024, 256, 0, stream>>>(z, bias, out);
}

// Round 6
// 366.609 us; speedup vs baseline: 5.3785x; 5.3785x over previous
//
#include <hip/hip_runtime.h>
#include <hip/hip_bf16.h>

// Match numpy: no FMA contraction anywhere that feeds the Jacobi pivots.
#pragma clang fp contract(off)

#define N 4096
#define CIN 64
#define COUT 64
#define ITERS 10
#define MAXS 40

typedef unsigned long long u64;

// pack (|value|, col j): bigger value wins; tie -> smaller j
__device__ __forceinline__ u64 packkey(float v, unsigned j) {
    return ((u64)__float_as_uint(v) << 32) | (u64)(~j);
}

// ---------- setup ----------
__global__ void edges1_k(const int* __restrict__ ei, int* __restrict__ deg, int E) {
    int e = blockIdx.x * 256 + threadIdx.x;
    if (e < E) atomicAdd(&deg[ei[e]], 1);
}

__global__ void __launch_bounds__(1024) scan_k(const int* __restrict__ deg,
                                               int* __restrict__ rowptr,
                                               float* __restrict__ dinv) {
    __shared__ int ps[1024];
    int t = threadIdx.x, b = t * 4;
    int d0 = deg[b], d1 = deg[b + 1], d2 = deg[b + 2], d3 = deg[b + 3];
    int local = d0 + d1 + d2 + d3;
    ps[t] = local;
    __syncthreads();
    for (int off = 1; off < 1024; off <<= 1) {
        int v = (t >= off) ? ps[t - off] : 0;
        __syncthreads();
        ps[t] += v;
        __syncthreads();
    }
    int excl = ps[t] - local;
    rowptr[b] = excl; rowptr[b + 1] = excl + d0;
    rowptr[b + 2] = excl + d0 + d1; rowptr[b + 3] = excl + d0 + d1 + d2;
    if (t == 1023) rowptr[4096] = ps[1023];
    dinv[b]     = d0 > 0 ? 1.0f / sqrtf((float)d0) : 0.0f;
    dinv[b + 1] = d1 > 0 ? 1.0f / sqrtf((float)d1) : 0.0f;
    dinv[b + 2] = d2 > 0 ? 1.0f / sqrtf((float)d2) : 0.0f;
    dinv[b + 3] = d3 > 0 ? 1.0f / sqrtf((float)d3) : 0.0f;
}

__global__ void edges2_k(const int* __restrict__ ei, const int* __restrict__ rowptr,
                         int* __restrict__ fill, int* __restrict__ colidx, int E) {
    int e = blockIdx.x * 256 + threadIdx.x;
    if (e < E) {
        int r = ei[e], c = ei[E + e];
        int pos = rowptr[r] + atomicAdd(&fill[r], 1);
        colidx[pos] = c;
    }
}

__global__ void prepw_k(const float* __restrict__ hh, const float* __restrict__ cw,
                        const float* __restrict__ rw, const float* __restrict__ iw,
                        float2* __restrict__ hcT, float4* __restrict__ rwT,
                        float4* __restrict__ iwT) {
    int idx = blockIdx.x * 256 + threadIdx.x;
    int i = idx >> 6, o = idx & 63;
    int src = o * 64 + i;
    hcT[idx] = make_float2(hh[src], cw[src]);
    rwT[idx] = make_float4(rw[src * 4 + 0], rw[src * 4 + 1], rw[src * 4 + 2], rw[src * 4 + 3]);
    iwT[idx] = make_float4(iw[src * 4 + 0], iw[src * 4 + 1], iw[src * 4 + 2], iw[src * 4 + 3]);
}

// per-row max of |L_ij| (j>i), diag, and y=x copy. One block per row.
__global__ void __launch_bounds__(128) rowmax0_k(
        const int* __restrict__ rowptr, const int* __restrict__ colidx,
        const float* __restrict__ dinv, const float* __restrict__ x,
        float* __restrict__ y, float* __restrict__ diag,
        u64* __restrict__ rowmax, float* __restrict__ rowval) {
    const int i = blockIdx.x, t = threadIdx.x;
    __shared__ float row[N];
    __shared__ u64 w2[2];
    for (int j = t; j < N; j += 128) row[j] = 0.0f;
    __syncthreads();
    for (int e = rowptr[i] + t; e < rowptr[i + 1]; e += 128)
        atomicAdd(&row[colidx[e]], 1.0f);
    __syncthreads();
    float di = dinv[i];
    u64 best = packkey(0.0f, 4095u);
    for (int j = t; j < N; j += 128) {
        if (j > i) {
            float v = -((di * row[j]) * dinv[j]);
            u64 kk = packkey(fabsf(v), (unsigned)j);
            if (kk > best) best = kk;
        }
    }
    for (int off = 32; off; off >>= 1) { u64 o = __shfl_down(best, off, 64); if (o > best) best = o; }
    if ((t & 63) == 0) w2[t >> 6] = best;
    __syncthreads();
    if (t == 0) {
        u64 b = w2[0]; if (w2[1] > b) b = w2[1];
        unsigned js = (~(unsigned)b) & 4095u;
        rowmax[i] = b;
        rowval[i] = -((di * row[js]) * dinv[js]);
        diag[i] = 1.0f - ((di * row[i]) * di);
    }
    if (t < CIN) y[i * CIN + t] = x[i * CIN + t];
}

// ---------- per-iteration: pivot + build/rotate rows & cols k,l ----------
__global__ void __launch_bounds__(1024) rowbuild_k(
        const int* __restrict__ rowptr, const int* __restrict__ colidx,
        const float* __restrict__ dinv,
        float* __restrict__ diag, u64* __restrict__ rowmax, float* __restrict__ rowval,
        float* __restrict__ y,
        float* __restrict__ rowS, float* __restrict__ colS,
        int* __restrict__ dslot, int* __restrict__ slist, int* __restrict__ nslots,
        int* __restrict__ rotk, int* __restrict__ rotl,
        float* __restrict__ rotc, float* __restrict__ rotsv, int it) {
    __shared__ float bufK[N], bufL[N];
    __shared__ u64 w16[16], w16b[16];
    __shared__ float sRowKjs[MAXS], sRowLjs[MAXS];
    __shared__ int S_k, S_l, S_slotk, S_slotl, S_oldk, S_oldl, S_nold;
    __shared__ float S_c, S_s, S_a2kk, S_a2ll;
    const int t = threadIdx.x;

    // Phase 0: pivot selection (val desc, flat idx asc = np.argmax row-major)
    u64 best = 0ull;
    for (int r = t; r < N; r += 1024) {
        u64 p = rowmax[r];
        unsigned vb = (unsigned)(p >> 32);
        unsigned j = (~(unsigned)p) & 4095u;
        unsigned flat = ((unsigned)r << 12) | j;
        u64 key = ((u64)vb << 24) | (u64)((~flat) & 0xFFFFFFu);
        if (key > best) best = key;
    }
    for (int off = 32; off; off >>= 1) { u64 o = __shfl_down(best, off, 64); if (o > best) best = o; }
    if ((t & 63) == 0) w16[t >> 6] = best;
    __syncthreads();
    if (t == 0) {
        u64 b = w16[0];
        for (int w = 1; w < 16; ++w) if (w16[w] > b) b = w16[w];
        unsigned flat = (~(unsigned)b) & 0xFFFFFFu;
        int k = (int)(flat >> 12), l = (int)(flat & 4095u);
        float akl = rowval[k];
        float akk = diag[k], all_ = diag[l];
        float aDiff = all_ - akk;
        float akl_safe = (akl == 0.0f) ? 1.0f : akl;
        float aDiff_safe = (aDiff == 0.0f) ? 1.0f : aDiff;
        float phi = aDiff / (2.0f * akl_safe);
        float t2 = 1.0f / (fabsf(phi) + sqrtf(phi * phi + 1.0f));
        t2 = (phi < 0.0f) ? -t2 : t2;
        float t1 = akl / aDiff_safe;
        float tt = (fabsf(akl) < fabsf(aDiff) * 1e-36f) ? t1 : t2;
        float cv = 1.0f / sqrtf(tt * tt + 1.0f);
        float sv = tt * cv;
        rotk[it] = k; rotl[it] = l; rotc[it] = cv; rotsv[it] = sv;
        int ns = *nslots;
        S_nold = ns;
        int ok = dslot[k]; S_oldk = ok;
        int sk = ok; if (ok < 0) { sk = ns; slist[ns] = k; dslot[k] = ns; ns++; }
        int ol = dslot[l]; S_oldl = ol;
        int sl = ol; if (ol < 0) { sl = ns; slist[ns] = l; dslot[l] = ns; ns++; }
        *nslots = ns;
        S_k = k; S_l = l; S_slotk = sk; S_slotl = sl; S_c = cv; S_s = sv;
    }
    __syncthreads();
    const int k = S_k, l = S_l, slotk = S_slotk, slotl = S_slotl;
    const int oldk = S_oldk, oldl = S_oldl, nold = S_nold;
    const float c = S_c, s = S_s;
    if (t < CIN) {  // incremental U^T x
        float yk = y[k * CIN + t], yl = y[l * CIN + t];
        y[k * CIN + t] = c * yk - s * yl;
        y[l * CIN + t] = s * yk + c * yl;
    }
    const float dk = dinv[k], dl = dinv[l];

    // Phase A: edge counts for fresh rows
    for (int j = t; j < N; j += 1024) { bufK[j] = 0.0f; bufL[j] = 0.0f; }
    __syncthreads();
    if (oldk < 0) for (int e = rowptr[k] + t; e < rowptr[k + 1]; e += 1024) atomicAdd(&bufK[colidx[e]], 1.0f);
    if (oldl < 0) for (int e = rowptr[l] + t; e < rowptr[l + 1]; e += 1024) atomicAdd(&bufL[colidx[e]], 1.0f);
    __syncthreads();
    // Phase B: old rows k,l (reference orientation a_kj / a_lj)
    for (int j = t; j < N; j += 1024) {
        float vk = (oldk >= 0) ? rowS[(size_t)oldk * N + j] : -((dk * bufK[j]) * dinv[j]);
        float vl = (oldl >= 0) ? rowS[(size_t)oldl * N + j] : -((dl * bufL[j]) * dinv[j]);
        bufK[j] = vk; bufL[j] = vl;
    }
    __syncthreads();
    if (t < nold) {  // overlay prior-pivot columns (exact stored a_kj = colS_j[k])
        int js = slist[t];
        if (oldk < 0) bufK[js] = colS[(size_t)t * N + k];
        if (oldl < 0) bufL[js] = colS[(size_t)t * N + l];
    }
    __syncthreads();
    if (t == 0) {
        bufK[k] = diag[k]; bufL[l] = diag[l];
        float akk = bufK[k], all_ = bufL[l], akl = bufK[l], alk = bufL[k];
        float a1kk = c * akk - s * akl;
        float a1kl = s * akk + c * akl;
        float a1lk = c * alk - s * all_;
        float a1ll = s * alk + c * all_;
        S_a2kk = c * a1kk - s * a1lk;
        S_a2ll = s * a1kl + c * a1ll;
        diag[k] = S_a2kk; diag[l] = S_a2ll;
    }
    __syncthreads();
    const float a2kk = S_a2kk, a2ll = S_a2ll;
    // Phase B3: rotate rows in place, write, rowmax for rows k,l
    u64 bk = packkey(0.0f, 4095u), bl = packkey(0.0f, 4095u);
    for (int j = t; j < N; j += 1024) {
        float rk = bufK[j], rl = bufL[j], nk, nl;
        if (j == k)      { nk = a2kk; nl = 0.0f; }
        else if (j == l) { nk = 0.0f; nl = a2ll; }
        else             { nk = c * rk - s * rl; nl = s * rk + c * rl; }
        bufK[j] = nk; bufL[j] = nl;
        rowS[(size_t)slotk * N + j] = nk;
        rowS[(size_t)slotl * N + j] = nl;
        if (j > k) { u64 kk = packkey(fabsf(nk), (unsigned)j); if (kk > bk) bk = kk; }
        if (j > l) { u64 kk = packkey(fabsf(nl), (unsigned)j); if (kk > bl) bl = kk; }
    }
    __syncthreads();
    if (t < nold) {  // capture new-row values at old-pivot columns for Phase D
        int js = slist[t];
        sRowKjs[t] = bufK[js];
        sRowLjs[t] = bufL[js];
    }
    for (int off = 32; off; off >>= 1) {
        u64 o = __shfl_down(bk, off, 64); if (o > bk) bk = o;
        u64 o2 = __shfl_down(bl, off, 64); if (o2 > bl) bl = o2;
    }
    if ((t & 63) == 0) { w16[t >> 6] = bk; w16b[t >> 6] = bl; }
    __syncthreads();
    if (t == 0) {
        u64 b1 = w16[0], b2 = w16b[0];
        for (int w = 1; w < 16; ++w) { if (w16[w] > b1) b1 = w16[w]; if (w16b[w] > b2) b2 = w16b[w]; }
        unsigned j1 = (~(unsigned)b1) & 4095u, j2 = (~(unsigned)b2) & 4095u;
        rowmax[k] = b1; rowval[k] = bufK[j1];
        rowmax[l] = b2; rowval[l] = bufL[j2];
    }
    __syncthreads();
    // Phase C: columns k,l (reference orientation a_jk / a_jl)
    for (int j = t; j < N; j += 1024) { bufK[j] = 0.0f; bufL[j] = 0.0f; }
    __syncthreads();
    if (oldk < 0) for (int e = rowptr[k] + t; e < rowptr[k + 1]; e += 1024) atomicAdd(&bufK[colidx[e]], 1.0f);
    if (oldl < 0) for (int e = rowptr[l] + t; e < rowptr[l + 1]; e += 1024) atomicAdd(&bufL[colidx[e]], 1.0f);
    __syncthreads();
    for (int j = t; j < N; j += 1024) {
        float vk = (oldk >= 0) ? colS[(size_t)oldk * N + j] : -((dinv[j] * bufK[j]) * dk);
        float vl = (oldl >= 0) ? colS[(size_t)oldl * N + j] : -((dinv[j] * bufL[j]) * dl);
        bufK[j] = vk; bufL[j] = vl;
    }
    __syncthreads();
    if (t < nold) {  // overlay a_jk = rowS_js[k] for prior pivots (skip k,l)
        int js = slist[t];
        if (js != k && js != l) {
            if (oldk < 0) bufK[js] = rowS[(size_t)t * N + k];
            if (oldl < 0) bufL[js] = rowS[(size_t)t * N + l];
        }
    }
    __syncthreads();
    for (int j = t; j < N; j += 1024) {
        float ck_ = bufK[j], cl_ = bufL[j], nk, nl;
        if (j == k)      { nk = a2kk; nl = 0.0f; }
        else if (j == l) { nk = 0.0f; nl = a2ll; }
        else             { nk = c * ck_ - s * cl_; nl = s * ck_ + c * cl_; }
        colS[(size_t)slotk * N + j] = nk;
        colS[(size_t)slotl * N + j] = nl;
    }
    // Phase D: patch old slots' entries at rows/cols k,l (exact copies)
    if (t < nold) {
        int js = slist[t];
        if (js != k && js != l) {
            colS[(size_t)t * N + k] = sRowKjs[t];               // a_{k,js}
            colS[(size_t)t * N + l] = sRowLjs[t];               // a_{l,js}
            rowS[(size_t)t * N + k] = c * bufK[js] - s * bufL[js]; // a_{js,k}
            rowS[(size_t)t * N + l] = s * bufK[js] + c * bufL[js]; // a_{js,l}
        }
    }
}

// ---------- per-iteration: merge rowmax for all other rows ----------
__global__ void __launch_bounds__(128) merge_k(
        const int* __restrict__ rowptr, const int* __restrict__ colidx,
        const float* __restrict__ dinv,
        const float* __restrict__ rowS, const float* __restrict__ colS,
        u64* __restrict__ rowmax, float* __restrict__ rowval,
        const int* __restrict__ dslot, const int* __restrict__ slist,
        const int* __restrict__ nslots,
        const int* __restrict__ rotk, const int* __restrict__ rotl, int it) {
    const int t = threadIdx.x;
    const int k = rotk[it], l = rotl[it];
    const int slotk = dslot[k], slotl = dslot[l];
    __shared__ int sdirty[128];
    __shared__ int snd;
    __shared__ float row[N];
    __shared__ u64 w2[2];
    if (t == 0) snd = 0;
    __syncthreads();
    int i = blockIdx.x * 128 + t;
    if (i != k && i != l) {
        float nik = colS[(size_t)slotk * N + i];   // new a_{i,k}
        float nil = colS[(size_t)slotl * N + i];   // new a_{i,l}
        u64 cached = rowmax[i];
        unsigned cj = (~(unsigned)cached) & 4095u;
        bool kc = (k > i), lc = (l > i);
        u64 ck_ = kc ? packkey(fabsf(nik), (unsigned)k) : 0ull;
        u64 cl_ = lc ? packkey(fabsf(nil), (unsigned)l) : 0ull;
        bool stale = false; u64 base = cached; bool useOld = true;
        if (kc && cj == (unsigned)k)      { if (ck_ < cached) stale = true; else { base = 0ull; useOld = false; } }
        else if (lc && cj == (unsigned)l) { if (cl_ < cached) stale = true; else { base = 0ull; useOld = false; } }
        if (!stale) {
            if (kc || lc) {
                u64 m = base; float mv = useOld ? rowval[i] : 0.0f;
                if (ck_ > m) { m = ck_; mv = nik; }
                if (cl_ > m) { m = cl_; mv = nil; }
                rowmax[i] = m; rowval[i] = mv;
            }
        } else {
            int d = atomicAdd(&snd, 1);
            sdirty[d] = i;
        }
    }
    __syncthreads();
    int nd = snd;
    int ns = *nslots;
    for (int d = 0; d < nd; ++d) {
        int ir = sdirty[d];
        int slot = dslot[ir];       // block-uniform
        u64 best = packkey(0.0f, 4095u);
        if (slot >= 0) {            // former pivot: dense row stored & patched
            for (int j = t; j < N; j += 128) {
                if (j > ir) {
                    float v = rowS[(size_t)slot * N + j];
                    u64 kk = packkey(fabsf(v), (unsigned)j);
                    if (kk > best) best = kk;
                }
            }
            for (int off = 32; off; off >>= 1) { u64 o = __shfl_down(best, off, 64); if (o > best) best = o; }
            if ((t & 63) == 0) w2[t >> 6] = best;
            __syncthreads();
            if (t == 0) {
                u64 b = w2[0]; if (w2[1] > b) b = w2[1];
                unsigned js = (~(unsigned)b) & 4095u;
                rowmax[ir] = b; rowval[ir] = rowS[(size_t)slot * N + js];
            }
            __syncthreads();
        } else {                    // rebuild row ir from CSR + S overlays
            for (int j = t; j < N; j += 128) row[j] = 0.0f;
            __syncthreads();
            for (int e = rowptr[ir] + t; e < rowptr[ir + 1]; e += 128)
                atomicAdd(&row[colidx[e]], 1.0f);
            __syncthreads();
            float di = dinv[ir];
            for (int j = t; j < N; j += 128) row[j] = -((di * row[j]) * dinv[j]);
            __syncthreads();
            if (t < ns) { int js = slist[t]; if (js != ir) row[js] = colS[(size_t)t * N + ir]; }
            __syncthreads();
            for (int j = t; j < N; j += 128) {
                if (j > ir) { u64 kk = packkey(fabsf(row[j]), (unsigned)j); if (kk > best) best = kk; }
            }
            for (int off = 32; off; off >>= 1) { u64 o = __shfl_down(best, off, 64); if (o > best) best = o; }
            if ((t & 63) == 0) w2[t >> 6] = best;
            __syncthreads();
            if (t == 0) {
                u64 b = w2[0]; if (w2[1] > b) b = w2[1];
                unsigned js = (~(unsigned)b) & 4095u;
                rowmax[ir] = b; rowval[ir] = row[js];
            }
            __syncthreads();
        }
    }
}

// ---------- tail ----------
__global__ void __launch_bounds__(1024) spectral_k(
        const float* __restrict__ diag, const float* __restrict__ y,
        const float2* __restrict__ hcT, const float4* __restrict__ rwT,
        const float4* __restrict__ iwT, float* __restrict__ z) {
    int o = threadIdx.x & 63;
    int nl = threadIdx.x >> 6;
    int n = blockIdx.x * 16 + nl;
    __shared__ float saux[16][CIN];
    saux[nl][o] = y[n * CIN + o];
    __syncthreads();
    float wn = diag[n];
    const float C2 = -0.41614683654714241f;   // cos(2.0)
    const float S2 = 0.90929742682568170f;    // sin(2.0)
    float acc = 0.0f;
    for (int i = 0; i < CIN; ++i) {
        float2 hc = hcT[i * 64 + o];
        float hw = hc.x * wn;
        float t2v = hw * hw;
        float inv = 1.0f / (t2v + 1.0f);
        float c1 = (t2v - 1.0f) * inv;
        float s1 = (2.0f * hw) * inv;
        if (!(hw > 1e-5f)) { c1 = C2; s1 = S2; }
        float4 rwv = rwT[i * 64 + o];
        float4 iwv = iwT[i * 64 + o];
        float g = hc.y;
        float cj = c1, sj = s1;
        g += rwv.x * cj - iwv.x * sj;
        float cn = cj * c1 - sj * s1; float sn = sj * c1 + cj * s1; cj = cn; sj = sn;
        g += rwv.y * cj - iwv.y * sj;
        cn = cj * c1 - sj * s1; sn = sj * c1 + cj * s1; cj = cn; sj = sn;
        g += rwv.z * cj - iwv.z * sj;
        cn = cj * c1 - sj * s1; sn = sj * c1 + cj * s1; cj = cn; sj = sn;
        g += rwv.w * cj - iwv.w * sj;
        acc += g * saux[nl][i];
    }
    z[(size_t)n * COUT + o] = acc;
}

__global__ void finalrot_k(float* __restrict__ z,
                           const int* __restrict__ rotk, const int* __restrict__ rotl,
                           const float* __restrict__ rotc, const float* __restrict__ rotsv) {
    int col = threadIdx.x;
    for (int i = ITERS - 1; i >= 0; --i) {
        int k = rotk[i], l = rotl[i];
        float c = rotc[i], s = rotsv[i];
        float zk = z[k * COUT + col];
        float zl = z[l * COUT + col];
        z[k * COUT + col] = c * zk + s * zl;
        z[l * COUT + col] = -s * zk + c * zl;
    }
}

__global__ void store_k(const float* __restrict__ z, const float* __restrict__ bias,
                        float* __restrict__ out) {
    int idx = blockIdx.x * 256 + threadIdx.x;
    if (idx < N * COUT) out[idx] = z[idx] + bias[idx & 63];
}

extern "C" void kernel_launch(void* const* d_in, const int* in_sizes, int n_in,
                              void* d_out, int out_size, void* d_ws, size_t ws_size,
                              hipStream_t stream) {
    const float* x   = (const float*)d_in[0];
    const int*   ei  = (const int*)d_in[1];
    const float* rw  = (const float*)d_in[2];
    const float* iw  = (const float*)d_in[3];
    const float* hh  = (const float*)d_in[4];
    const float* cw  = (const float*)d_in[5];
    const float* bias= (const float*)d_in[6];
    float* out = (float*)d_out;

    // Workspace carve (~7.5 MB)
    float* rowS = (float*)d_ws;                 // MAXS*N
    float* colS = rowS + (size_t)MAXS * N;      // MAXS*N
    float* y    = colS + (size_t)MAXS * N;      // N*CIN
    float* z    = y + N * CIN;                  // N*COUT
    float2* hcT = (float2*)(z + N * COUT);      // 4096 float2
    float4* rwT = (float4*)(hcT + 4096);        // 4096 float4
    float4* iwT = rwT + 4096;                   // 4096 float4
    float* dinv = (float*)(iwT + 4096);         // 4096
    float* diag = dinv + N;                     // 4096
    float* rowval = diag + N;                   // 4096
    u64* rowmax = (u64*)(rowval + N);           // 4096 u64
    int* rowptr = (int*)(rowmax + N);           // 4100
    int* fill   = rowptr + 4100;                // 4096  <- zero from here
    int* deg    = fill + N;                     // 4096
    int* slist  = deg + N;                      // 64
    int* nslots = slist + 64;                   // 4     <- zero to here
    int* dslot  = nslots + 4;                   // 4096  <- 0xFF
    int* rotk   = dslot + N;                    // 16
    int* rotl   = rotk + 16;                    // 16
    float* rotc = (float*)(rotl + 16);          // 16
    float* rotsv= rotc + 16;                    // 16
    int* colidx = (int*)(rotsv + 16);           // 400000

    int E = in_sizes[1] / 2;                    // 400000 (row half of edge_index)
    int eb = (E + 255) / 256;

    hipMemsetAsync(fill, 0, (size_t)(N + N + 64 + 4) * 4, stream);
    hipMemsetAsync(dslot, 0xFF, (size_t)N * 4, stream);

    edges1_k<<<eb, 256, 0, stream>>>(ei, deg, E);
    scan_k<<<1, 1024, 0, stream>>>(deg, rowptr, dinv);
    edges2_k<<<eb, 256, 0, stream>>>(ei, rowptr, fill, colidx, E);
    prepw_k<<<16, 256, 0, stream>>>(hh, cw, rw, iw, hcT, rwT, iwT);
    rowmax0_k<<<N, 128, 0, stream>>>(rowptr, colidx, dinv, x, y, diag, rowmax, rowval);

    for (int it = 0; it < ITERS; ++it) {
        rowbuild_k<<<1, 1024, 0, stream>>>(rowptr, colidx, dinv, diag, rowmax, rowval,
                                           y, rowS, colS, dslot, slist, nslots,
                                           rotk, rotl, rotc, rotsv, it);
        merge_k<<<32, 128, 0, stream>>>(rowptr, colidx, dinv, rowS, colS,
                                        rowmax, rowval, dslot, slist, nslots,
                                        rotk, rotl, it);
    }

    spectral_k<<<N / 16, 1024, 0, stream>>>(diag, y, hcT, rwT, iwT, z);
    finalrot_k<<<1, 64, 0, stream>>>(z, rotk, rotl, rotc, rotsv);
    store_k<<<1024, 256, 0, stream>>>(z, bias, out);
}